// Round 2
// baseline (827.643 us; speedup 1.0000x reference)
//
#include <hip/hip_runtime.h>
#include <math.h>

#define NUM_DET   100
#define CAP       2048
#define SCORE_TH  0.05f
#define NMS_TH    0.5f
#define MIN_SIZE  1.0f
#define BBOX_CLIP 4.135166556742356f   // log(1000/16)

// image_h / image_w arrive as 1-element device arrays; dtype may be int32 or
// f32 depending on harness convention. Small positive int => int32.
__device__ __forceinline__ float sc_to_f(const void* p) {
    int iv = *(const int*)p;
    return (iv > 0 && iv < 1000000) ? (float)iv : *(const float*)p;
}

__device__ __forceinline__ float wmaxf(float v) {
#pragma unroll
    for (int off = 32; off > 0; off >>= 1) v = fmaxf(v, __shfl_xor(v, off, 64));
    return v;
}
__device__ __forceinline__ float wsumf(float v) {
#pragma unroll
    for (int off = 32; off > 0; off >>= 1) v += __shfl_xor(v, off, 64);
    return v;
}

// Faster R-CNN BoxCoder.decode, contraction off to track XLA elementwise
// (unfused mul/add) semantics as closely as possible.
__device__ __forceinline__ void decode4(float d0, float d1, float d2, float d3,
                                        float x1, float y1, float x2, float y2,
                                        float& ox1, float& oy1, float& ox2, float& oy2) {
#pragma clang fp contract(off)
    float wd = x2 - x1, ht = y2 - y1;
    float cx = x1 + 0.5f * wd, cy = y1 + 0.5f * ht;
    float dx = d0 / 10.0f, dy = d1 / 10.0f;
    float dw = fminf(d2 / 5.0f, BBOX_CLIP), dh = fminf(d3 / 5.0f, BBOX_CLIP);
    float pcx = dx * wd + cx, pcy = dy * ht + cy;
    float pw = expf(dw) * wd, ph = expf(dh) * ht;
    ox1 = pcx - 0.5f * pw; oy1 = pcy - 0.5f * ph;
    ox2 = pcx + 0.5f * pw; oy2 = pcy + 0.5f * ph;
}

// ---------------- kernel 1: softmax + per-class candidate compaction ----------
// one wave (64 lanes) per proposal row
__global__ __launch_bounds__(256) void collect_kernel(
    const float* __restrict__ logits, const float* __restrict__ breg,
    const float* __restrict__ prop, const void* phh, const void* pww,
    int N, int C,
    int* __restrict__ counts, int* __restrict__ cidx,
    float* __restrict__ cscore, float4* __restrict__ cbox) {
    int gw   = (blockIdx.x * blockDim.x + threadIdx.x) >> 6;
    int lane = threadIdx.x & 63;
    if (gw >= N) return;
    float h = sc_to_f(phh), w = sc_to_f(pww);
    const float* row = logits + (size_t)gw * C;
    float m = -INFINITY;
    for (int c = lane; c < C; c += 64) m = fmaxf(m, row[c]);
    m = wmaxf(m);
    float s = 0.f;
    for (int c = lane; c < C; c += 64) s += expf(row[c] - m);
    s = wsumf(s);
    float px1 = prop[gw * 4 + 0], py1 = prop[gw * 4 + 1];
    float px2 = prop[gw * 4 + 2], py2 = prop[gw * 4 + 3];
    for (int c = lane + 1; c < C; c += 64) {   // classes 1..C-1
        float score = expf(row[c] - m) / s;
        if (score >= SCORE_TH) {
            const float* d = breg + (size_t)gw * 4 * C + 4 * c;
            float bx1, by1, bx2, by2;
            decode4(d[0], d[1], d[2], d[3], px1, py1, px2, py2, bx1, by1, bx2, by2);
            bx1 = fminf(fmaxf(bx1, 0.f), w); by1 = fminf(fmaxf(by1, 0.f), h);
            bx2 = fminf(fmaxf(bx2, 0.f), w); by2 = fminf(fmaxf(by2, 0.f), h);
            if (bx2 - bx1 >= MIN_SIZE && by2 - by1 >= MIN_SIZE) {
                int cc  = c - 1;
                int pos = atomicAdd(&counts[cc], 1);
                if (pos < CAP) {
                    cidx[cc * CAP + pos]   = gw;
                    cscore[cc * CAP + pos] = score;
                    cbox[cc * CAP + pos]   = make_float4(bx1, by1, bx2, by2);
                }
            }
        }
    }
}

// ---------------- kernel 2: greedy NMS, one block per class ------------------
__global__ __launch_bounds__(256) void nms_kernel(
    const int* __restrict__ counts, const int* __restrict__ cidx,
    const float* __restrict__ cscore, const float4* __restrict__ cbox,
    int* __restrict__ keep_idx, int* __restrict__ keep_valid) {
    __shared__ float  ssc[CAP];
    __shared__ float4 sbox[CAP];
    __shared__ int    sidx[CAP];
    __shared__ float  rs[256];
    __shared__ int    rio[256], rjj[256];
    int cc  = blockIdx.x;
    int t   = threadIdx.x;
    int cnt = min(counts[cc], CAP);
    for (int i = t; i < cnt; i += 256) {
        ssc[i]  = cscore[cc * CAP + i];
        sbox[i] = cbox[cc * CAP + i];
        sidx[i] = cidx[cc * CAP + i];
    }
    __syncthreads();
    for (int it = 0; it < NUM_DET; ++it) {
        // argmax over (score desc, orig idx asc)  == jnp.argmax first-index
        float bs = -INFINITY; int bi = 0x7fffffff; int bj = -1;
        for (int i = t; i < cnt; i += 256) {
            float sc = ssc[i]; int oi = sidx[i];
            if (sc > bs || (sc == bs && oi < bi)) { bs = sc; bi = oi; bj = i; }
        }
        rs[t] = bs; rio[t] = bi; rjj[t] = bj;
        __syncthreads();
        for (int off = 128; off > 0; off >>= 1) {
            if (t < off) {
                float s2 = rs[t + off]; int i2 = rio[t + off];
                if (s2 > rs[t] || (s2 == rs[t] && i2 < rio[t])) {
                    rs[t] = s2; rio[t] = i2; rjj[t] = rjj[t + off];
                }
            }
            __syncthreads();
        }
        float bscore = rs[0];
        if (bscore > -INFINITY) {
            int bslot = rjj[0];
            if (t == 0) { keep_idx[cc * NUM_DET + it] = rio[0]; keep_valid[cc * NUM_DET + it] = 1; }
            float4 bb = sbox[bslot];
            {
#pragma clang fp contract(off)
                float areab = (bb.z - bb.x) * (bb.w - bb.y);
                for (int i = t; i < cnt; i += 256) {
                    float4 b  = sbox[i];
                    float ltx = fmaxf(bb.x, b.x), lty = fmaxf(bb.y, b.y);
                    float rbx = fminf(bb.z, b.z), rby = fminf(bb.w, b.w);
                    float iw  = fmaxf(rbx - ltx, 0.f), ih = fmaxf(rby - lty, 0.f);
                    float inter = iw * ih;
                    float area  = (b.z - b.x) * (b.w - b.y);
                    float iou   = inter / (areab + area - inter + 1e-9f);
                    if (iou > NMS_TH) ssc[i] = -INFINITY;
                }
            }
        } else {
            // all suppressed / empty: reference argmax of all -inf returns 0
            if (t == 0) { keep_idx[cc * NUM_DET + it] = 0; keep_valid[cc * NUM_DET + it] = 0; }
        }
        __syncthreads();
    }
}

// ---------------- kernel 3: epilogue — recompute + gather outputs ------------
// one wave per output slot (class cc, rank k). Writes ALL of d_out.
__global__ __launch_bounds__(256) void output_kernel(
    const float* __restrict__ logits, const float* __restrict__ breg,
    const float* __restrict__ treg, const float* __restrict__ prop,
    const void* phh, const void* pww,
    const int* __restrict__ keep_idx, const int* __restrict__ keep_valid,
    int N, int C, int T, float* __restrict__ out) {
    int slot = (blockIdx.x * blockDim.x + threadIdx.x) >> 6;
    int lane = threadIdx.x & 63;
    int NC1 = C - 1;
    int M   = NC1 * NUM_DET;
    if (slot >= M) return;
    int cc = slot / NUM_DET;
    int c  = cc + 1;
    int p   = keep_idx[slot];
    int val = keep_valid[slot];
    const float* row = logits + (size_t)p * C;
    float m = -INFINITY;
    for (int j = lane; j < C; j += 64) m = fmaxf(m, row[j]);
    m = wmaxf(m);
    float s = 0.f;
    for (int j = lane; j < C; j += 64) s += expf(row[j] - m);
    s = wsumf(s);
    if (lane != 0) return;
    float h = sc_to_f(phh), w = sc_to_f(pww);
    float score = expf(row[c] - m) / s;
    float px1 = prop[p * 4 + 0], py1 = prop[p * 4 + 1];
    float px2 = prop[p * 4 + 2], py2 = prop[p * 4 + 3];
    // box
    const float* d = breg + (size_t)p * 4 * C + 4 * c;
    float bx1, by1, bx2, by2;
    decode4(d[0], d[1], d[2], d[3], px1, py1, px2, py2, bx1, by1, bx2, by2);
    out[slot * 4 + 0] = fminf(fmaxf(bx1, 0.f), w);
    out[slot * 4 + 1] = fminf(fmaxf(by1, 0.f), h);
    out[slot * 4 + 2] = fminf(fmaxf(bx2, 0.f), w);
    out[slot * 4 + 3] = fminf(fmaxf(by2, 0.f), h);
    out[4 * M + slot] = (float)c;        // labels
    out[5 * M + slot] = score;           // scores
    // trajectory: carry UNCLIPPED box, emit clipped per step
    float cx1 = px1, cy1 = py1, cx2 = px2, cy2 = py2;
    for (int tt = 0; tt < T; ++tt) {
        const float* td = treg + ((size_t)tt * N + p) * 4 * C + 4 * c;
        float nx1, ny1, nx2, ny2;
        decode4(td[0], td[1], td[2], td[3], cx1, cy1, cx2, cy2, nx1, ny1, nx2, ny2);
        int off = 6 * M + (tt * M + slot) * 4;
        out[off + 0] = fminf(fmaxf(nx1, 0.f), w);
        out[off + 1] = fminf(fmaxf(ny1, 0.f), h);
        out[off + 2] = fminf(fmaxf(nx2, 0.f), w);
        out[off + 3] = fminf(fmaxf(ny2, 0.f), h);
        cx1 = nx1; cy1 = ny1; cx2 = nx2; cy2 = ny2;
    }
    out[6 * M + 4 * T * M + slot] = val ? 1.0f : 0.0f;   // valid
}

extern "C" void kernel_launch(void* const* d_in, const int* in_sizes, int n_in,
                              void* d_out, int out_size, void* d_ws, size_t ws_size,
                              hipStream_t stream) {
    const float* logits = (const float*)d_in[0];
    const float* breg   = (const float*)d_in[1];
    const float* treg   = (const float*)d_in[2];
    const float* prop   = (const float*)d_in[3];
    const void*  phh    = d_in[4];
    const void*  pww    = d_in[5];
    int N   = in_sizes[3] / 4;                 // 50000
    int C   = in_sizes[0] / N;                 // 91
    int T   = in_sizes[2] / in_sizes[1];       // 3
    int NC1 = C - 1;

    // workspace layout (float4 block first for 16B alignment)
    char*   ws     = (char*)d_ws;
    float4* cbox   = (float4*)ws;                                    // NC1*CAP
    float*  cscore = (float*)(ws + (size_t)NC1 * CAP * 16);          // NC1*CAP
    int*    cidx   = (int*)  (ws + (size_t)NC1 * CAP * 20);          // NC1*CAP
    int*    counts = (int*)  (ws + (size_t)NC1 * CAP * 24);          // NC1
    int*    keep_idx   = counts + NC1;                               // NC1*NUM_DET
    int*    keep_valid = keep_idx + NC1 * NUM_DET;                   // NC1*NUM_DET

    (void)hipMemsetAsync(counts, 0, NC1 * sizeof(int), stream);

    collect_kernel<<<(N * 64 + 255) / 256, 256, 0, stream>>>(
        logits, breg, prop, phh, pww, N, C, counts, cidx, cscore, cbox);

    nms_kernel<<<NC1, 256, 0, stream>>>(counts, cidx, cscore, cbox, keep_idx, keep_valid);

    int M = NC1 * NUM_DET;
    output_kernel<<<(M * 64 + 255) / 256, 256, 0, stream>>>(
        logits, breg, treg, prop, phh, pww, keep_idx, keep_valid, N, C, T, (float*)d_out);
}